// Round 4
// baseline (223.709 us; speedup 1.0000x reference)
//
#include <hip/hip_runtime.h>
#include <math.h>

// Problem constants (reference: N=8192, D=200, k=100)
#define NN 8192
#define DD 200
#define KK 100

// s = b_i + e_j histogram grid: 1024 bins over [-8, 8), width 2^-6 (exact fp)
#define NBINS 1024
#define HSCALE 64.0f
#define BINW 0.015625f
#define CAND_CAP 4096
#define ROW_CAP 1024
#define COL_CAP 1024

// ws layout (4-byte word offsets)
#define OFF_B 0
#define OFF_E 8192
#define OFF_PB 16384   // 2048 per-block partials of sum(exp(b))
#define OFF_PE 18432   // 2048 per-block partials of sum(exp(e))

// DIAGNOSTIC ROUND (R4): in-kernel repetition to (a) surface both kernels in
// rocprof's top-5 (the 256 MiB re-poison fills at ~41 us otherwise hide them)
// and (b) decompose dur_us = overhead + 16*t_be + 8*t_tail. Fully idempotent:
// each rep recomputes and rewrites identical values; barriers prevent
// cross-rep shared-memory races. Compiler "memory" clobber per rep defeats
// cross-rep load hoisting so each rep re-issues its loads.
#define REPS_BE 16
#define REPS_TAIL 8

// K1: b[i] = G[i,:]·wb, e[i] = G[i,:]·we. One wave per row; 50 lanes × float4.
__global__ __launch_bounds__(256) void k_be(const float* __restrict__ G,
                                            const float* __restrict__ wb,
                                            const float* __restrict__ we,
                                            float* __restrict__ wsf) {
    __shared__ float seb[4], see[4];
    int gid = blockIdx.x * 256 + threadIdx.x;
    int row = gid >> 6;
    int lane = gid & 63;
    int wave = threadIdx.x >> 6;
    for (int rep = 0; rep < REPS_BE; ++rep) {
        asm volatile("" ::: "memory");
        float pb = 0.f, pe = 0.f;
        if (lane < 50) {
            float4 g = ((const float4*)(G + (size_t)row * DD))[lane];
            float4 B = ((const float4*)wb)[lane];
            float4 E = ((const float4*)we)[lane];
            pb = fmaf(g.x, B.x, fmaf(g.y, B.y, fmaf(g.z, B.z, g.w * B.w)));
            pe = fmaf(g.x, E.x, fmaf(g.y, E.y, fmaf(g.z, E.z, g.w * E.w)));
        }
        for (int off = 32; off; off >>= 1) {
            pb += __shfl_xor(pb, off, 64);
            pe += __shfl_xor(pe, off, 64);
        }
        if (lane == 0) {
            wsf[OFF_B + row] = pb;
            wsf[OFF_E + row] = pe;
            seb[wave] = expf(pb);
            see[wave] = expf(pe);
        }
        __syncthreads();
        if (threadIdx.x == 0) {
            wsf[OFF_PB + blockIdx.x] = (seb[0] + seb[1]) + (seb[2] + seb[3]);
            wsf[OFF_PE + blockIdx.x] = (see[0] + see[1]) + (see[2] + see[3]);
        }
        __syncthreads();
    }
}

// K2: single block, 1024 threads (R3 structure, body wrapped in REPS_TAIL).
__global__ __launch_bounds__(1024) void k_tail(const float* __restrict__ wsf,
                                               float* __restrict__ out) {
    __shared__ float    b_s[NN];          // 32 KB
    __shared__ float    e_s[NN];          // 32 KB
    __shared__ float    cv[CAND_CAP];     // 16 KB
    __shared__ unsigned ci[CAND_CAP];     // 16 KB
    __shared__ unsigned sfx[NBINS];       // hist_e -> suffix sums (in place)
    __shared__ unsigned hbl[NBINS];       // hist_b
    __shared__ int      rows_s[ROW_CAP];
    __shared__ float    rowb_s[ROW_CAP];
    __shared__ int      cols_s[COL_CAP];
    __shared__ float    cole_s[COL_CAP];
    __shared__ float    fr_sb[16], fr_se[16];
    __shared__ int      fr_eb[16], fr_bb[16];
    __shared__ unsigned wred[16], wtail_s[16];
    __shared__ unsigned nrows_s, ncols_s, ncand_s;
    __shared__ int      lo_s;
    __shared__ float    sums_s[4];        // sb, se, emax_ub, bmax_ub

    int tid = threadIdx.x, wave = tid >> 6, lane = tid & 63;

    for (int rep = 0; rep < REPS_TAIL; ++rep) {
        asm volatile("" ::: "memory");
        sfx[tid] = 0u; hbl[tid] = 0u;
        if (tid == 0) { nrows_s = 0u; ncols_s = 0u; ncand_s = 0u; lo_s = 0; }
        __syncthreads();

        // ---- Stage b,e (float4 copy) + LDS-atomic hists.
        const float4* b4 = (const float4*)(wsf + OFF_B);
        const float4* e4 = (const float4*)(wsf + OFF_E);
        for (int i = tid; i < NN / 4; i += 1024) {        // 2 iterations
            float4 bv = b4[i], ev = e4[i];
            ((float4*)b_s)[i] = bv;
            ((float4*)e_s)[i] = ev;
            int p;
            p = (int)fmaf(bv.x, HSCALE, 512.f); atomicAdd(&hbl[min(max(p,0),NBINS-1)], 1u);
            p = (int)fmaf(bv.y, HSCALE, 512.f); atomicAdd(&hbl[min(max(p,0),NBINS-1)], 1u);
            p = (int)fmaf(bv.z, HSCALE, 512.f); atomicAdd(&hbl[min(max(p,0),NBINS-1)], 1u);
            p = (int)fmaf(bv.w, HSCALE, 512.f); atomicAdd(&hbl[min(max(p,0),NBINS-1)], 1u);
            p = (int)fmaf(ev.x, HSCALE, 512.f); atomicAdd(&sfx[min(max(p,0),NBINS-1)], 1u);
            p = (int)fmaf(ev.y, HSCALE, 512.f); atomicAdd(&sfx[min(max(p,0),NBINS-1)], 1u);
            p = (int)fmaf(ev.z, HSCALE, 512.f); atomicAdd(&sfx[min(max(p,0),NBINS-1)], 1u);
            p = (int)fmaf(ev.w, HSCALE, 512.f); atomicAdd(&sfx[min(max(p,0),NBINS-1)], 1u);
        }

        // ---- Reduce per-block exp partials (fixed order).
        float psb = wsf[OFF_PB + tid] + wsf[OFF_PB + 1024 + tid];
        float pse = wsf[OFF_PE + tid] + wsf[OFF_PE + 1024 + tid];
        for (int off = 32; off; off >>= 1) {
            psb += __shfl_xor(psb, off, 64);
            pse += __shfl_xor(pse, off, 64);
        }
        if (lane == 0) { fr_sb[wave] = psb; fr_se[wave] = pse; }
        __syncthreads();    // hist atomics + fr_sb/fr_se complete

        // ---- Top-occupied-bin upper bounds + suffix-scan setup.
        unsigned hb = hbl[tid];
        unsigned he = sfx[tid];
        int ebin = (he != 0u) ? tid : -1;
        int bbin = (hb != 0u) ? tid : -1;
        for (int off = 32; off; off >>= 1) {
            ebin = max(ebin, __shfl_xor(ebin, off, 64));
            bbin = max(bbin, __shfl_xor(bbin, off, 64));
        }
        if (lane == 0) { fr_eb[wave] = ebin; fr_bb[wave] = bbin; }
        unsigned v = he;
        for (int off = 1; off < 64; off <<= 1) {
            unsigned t = __shfl_down(v, off, 64);
            if (lane + off < 64) v += t;
        }
        if (lane == 0) wtail_s[wave] = v;
        __syncthreads();
        if (tid == 0) {
            float a = 0.f, b = 0.f; int c = -1, d = -1;
            for (int i = 0; i < 16; ++i) {
                a += fr_sb[i]; b += fr_se[i];
                c = max(c, fr_eb[i]); d = max(d, fr_bb[i]);
            }
            sums_s[0] = a; sums_s[1] = b;
            sums_s[2] = -8.0f + (float)(c + 1) * BINW;   // >= true emax
            sums_s[3] = -8.0f + (float)(d + 1) * BINW;   // >= true bmax
            unsigned acc = 0, tails[16];
            for (int w = 15; w >= 0; --w) { tails[w] = acc; acc += wtail_s[w]; }
            for (int w = 0; w < 16; ++w) wtail_s[w] = tails[w];
        }
        __syncthreads();
        sfx[tid] = v + wtail_s[wave];
        __syncthreads();

        // ---- 16-ary descent for largest t with cnt(t) >= 2*KK.
        const unsigned TARGET = 2u * KK;
        int chunk = 64;
        for (int round = 0; round < 2; ++round) {
            int t = lo_s + (wave + 1) * chunk;
            unsigned c = 0;
            for (int k = 0; k < 16; ++k) {
                int p = lane + (k << 6);
                int idx = t + 512 - p;
                unsigned sv = (idx <= 0) ? sfx[0] : ((idx > NBINS - 1) ? 0u : sfx[idx]);
                c += hbl[p] * sv;
            }
            for (int off = 32; off; off >>= 1) c += __shfl_xor(c, off, 64);
            if (lane == 0) wred[wave] = c;
            __syncthreads();
            if (tid == 0) {
                for (int w = 15; w >= 0; --w)
                    if (wred[w] >= TARGET) { lo_s += (w + 1) * chunk; break; }
            }
            __syncthreads();
            chunk >>= 4;   // 64 -> 4
        }
        {   // bracket is 4 wide: evaluate lo+1..lo+3 with waves 0..2
            int t = lo_s + wave + 1;
            if (wave < 3) {
                unsigned c = 0;
                for (int k = 0; k < 16; ++k) {
                    int p = lane + (k << 6);
                    int idx = t + 512 - p;
                    unsigned sv = (idx <= 0) ? sfx[0] : ((idx > NBINS - 1) ? 0u : sfx[idx]);
                    c += hbl[p] * sv;
                }
                for (int off = 32; off; off >>= 1) c += __shfl_xor(c, off, 64);
                if (lane == 0) wred[wave] = c;
            }
            __syncthreads();
            if (tid == 0) {
                for (int w = 2; w >= 0; --w)
                    if (wred[w] >= TARGET) { lo_s += w + 1; break; }
            }
            __syncthreads();
        }
        float thr = -8.0f + (float)(lo_s - 1) * BINW;   // one-bin safety margin
        float emax = sums_s[2], bmax = sums_s[3];

        // ---- Row and column candidate lists (conservative supersets).
        for (int i = tid; i < NN; i += 1024) {
            float bv = b_s[i];
            if (bv + emax >= thr) {
                unsigned pos = atomicAdd(&nrows_s, 1u);
                if (pos < ROW_CAP) { rows_s[pos] = i; rowb_s[pos] = bv; }
            }
            float ev = e_s[i];
            if (ev + bmax >= thr) {
                unsigned pos = atomicAdd(&ncols_s, 1u);
                if (pos < COL_CAP) { cols_s[pos] = i; cole_s[pos] = ev; }
            }
        }
        __syncthreads();
        int nr = (int)min(nrows_s, (unsigned)ROW_CAP);
        int nc = (int)min(ncols_s, (unsigned)COL_CAP);

        // ---- Pair scan over nr x nc candidate grid, upper triangle (j >= r).
        int tot = nr * nc;
        for (int idx = tid; idx < tot; idx += 1024) {
            int ri = idx / nc, cj = idx - ri * nc;
            int r = rows_s[ri], j = cols_s[cj];
            if (j < r) continue;
            float s = rowb_s[ri] + cole_s[cj];
            if (s >= thr) {
                unsigned pos = atomicAdd(&ncand_s, 1u);
                if (pos < CAND_CAP) {
                    cv[pos] = s;
                    ci[pos] = ((unsigned)r << 13) | (unsigned)j;
                }
            }
        }
        __syncthreads();

        // ---- Rank-based top-100 (jax order: value desc, flat index asc).
        unsigned M = min(ncand_s, (unsigned)CAND_CAP);
        float inv_den = 1.0f / (sums_s[0] * sums_s[1]);
        for (unsigned c2 = tid; c2 < M; c2 += 1024) {
            float vv = cv[c2];
            unsigned fi = ci[c2];
            int rank = 0;
            for (unsigned m = 0; m < M; ++m) {
                float vm = cv[m];
                rank += (vm > vv) || (vm == vv && ci[m] < fi);
            }
            if (rank < KK) {
                out[2 * rank]     = (float)(fi >> 13);
                out[2 * rank + 1] = (float)(fi & 8191u);
                out[200 + rank]   = expf(vv) * inv_den;
            }
        }
        __syncthreads();
    }
}

extern "C" void kernel_launch(void* const* d_in, const int* in_sizes, int n_in,
                              void* d_out, int out_size, void* d_ws, size_t ws_size,
                              hipStream_t stream) {
    const float* G  = (const float*)d_in[0];
    const float* wb = (const float*)d_in[1];
    const float* we = (const float*)d_in[2];
    float* out = (float*)d_out;
    float* wsf = (float*)d_ws;

    hipLaunchKernelGGL(k_be, dim3(2048), dim3(256), 0, stream, G, wb, we, wsf);
    hipLaunchKernelGGL(k_tail, dim3(1), dim3(1024), 0, stream, wsf, out);
}

// Round 5
// 77.673 us; speedup vs baseline: 2.8801x; 2.8801x over previous
//
#include <hip/hip_runtime.h>
#include <math.h>

// Problem constants (reference: N=8192, D=200, k=100)
#define NN 8192
#define DD 200
#define KK 100

// s = b_i + e_j histogram grid: 1024 bins over [-8, 8), width 2^-6 (exact fp)
#define NBINS 1024
#define HSCALE 64.0f
#define BINW 0.015625f
#define CAND_CAP 4096
#define ROW_CAP 1024
#define COL_CAP 1024

// ws layout (4-byte word offsets)
#define OFF_B 0
#define OFF_E 8192
#define OFF_PB 16384   // 2048 per-block partials of sum(exp(b))
#define OFF_PE 18432   // 2048 per-block partials of sum(exp(e))

// K1: b[i] = G[i,:]·wb, e[i] = G[i,:]·we. One wave per row; 50 lanes × float4.
// Measured R4: ~1.24 us (~5.3 TB/s on G) — at the HBM floor; unchanged.
__global__ __launch_bounds__(256) void k_be(const float* __restrict__ G,
                                            const float* __restrict__ wb,
                                            const float* __restrict__ we,
                                            float* __restrict__ wsf) {
    __shared__ float seb[4], see[4];
    int gid = blockIdx.x * 256 + threadIdx.x;
    int row = gid >> 6;
    int lane = gid & 63;
    int wave = threadIdx.x >> 6;
    float pb = 0.f, pe = 0.f;
    if (lane < 50) {
        float4 g = ((const float4*)(G + (size_t)row * DD))[lane];
        float4 B = ((const float4*)wb)[lane];
        float4 E = ((const float4*)we)[lane];
        pb = fmaf(g.x, B.x, fmaf(g.y, B.y, fmaf(g.z, B.z, g.w * B.w)));
        pe = fmaf(g.x, E.x, fmaf(g.y, E.y, fmaf(g.z, E.z, g.w * E.w)));
    }
    for (int off = 32; off; off >>= 1) {
        pb += __shfl_xor(pb, off, 64);
        pe += __shfl_xor(pe, off, 64);
    }
    if (lane == 0) {
        wsf[OFF_B + row] = pb;
        wsf[OFF_E + row] = pe;
        seb[wave] = expf(pb);
        see[wave] = expf(pe);
    }
    __syncthreads();
    if (threadIdx.x == 0) {
        wsf[OFF_PB + blockIdx.x] = (seb[0] + seb[1]) + (seb[2] + seb[3]);
        wsf[OFF_PE + blockIdx.x] = (see[0] + see[1]) + (see[2] + see[3]);
    }
}

// Order-preserving float->uint (total order, matches > on non-NaN floats).
__device__ __forceinline__ unsigned ford(float f) {
    unsigned u = __float_as_uint(f);
    return u ^ ((u & 0x80000000u) ? 0xFFFFFFFFu : 0x80000000u);
}

// K2: single block, 1024 threads. R5: b/e live in registers (no 64 KB LDS
// staging), 2-way privatized hists, 32-ary 2-round descent (same exact t*),
// packed-key rank pass (one b64 broadcast read per comparison).
__global__ __launch_bounds__(1024) void k_tail(const float* __restrict__ wsf,
                                               float* __restrict__ out) {
    __shared__ unsigned long long kv[CAND_CAP];   // 32 KB packed (value,~idx)
    __shared__ unsigned hb_par[2][NBINS];         // 8 KB  ([0] becomes merged)
    __shared__ unsigned he_par[2][NBINS];         // 8 KB
    __shared__ unsigned sfx[NBINS];               // 4 KB  suffix sums of hist_e
    __shared__ int      rows_s[ROW_CAP];
    __shared__ float    rowb_s[ROW_CAP];
    __shared__ int      cols_s[COL_CAP];
    __shared__ float    cole_s[COL_CAP];
    __shared__ float    fr_sb[16], fr_se[16];
    __shared__ int      fr_eb[16], fr_bb[16];
    __shared__ unsigned wred[32], wtail_s[16];
    __shared__ unsigned nrows_s, ncols_s, ncand_s;
    __shared__ int      lo_s;
    __shared__ float    sums_s[4];                // sb, se, emax_ub, bmax_ub

    int tid = threadIdx.x, wave = tid >> 6, lane = tid & 63;
    int par = wave & 1;

    hb_par[0][tid] = 0u; hb_par[1][tid] = 0u;
    he_par[0][tid] = 0u; he_par[1][tid] = 0u;
    if (tid == 0) { nrows_s = 0u; ncols_s = 0u; ncand_s = 0u; lo_s = 0; }
    __syncthreads();

    // ---- Load b,e into REGISTERS (rows 4*tid..4*tid+3 and +4096 block) and
    // build 2-way privatized LDS hists. No b_s/e_s staging.
    float4 bv0 = ((const float4*)(wsf + OFF_B))[tid];
    float4 ev0 = ((const float4*)(wsf + OFF_E))[tid];
    float4 bv1 = ((const float4*)(wsf + OFF_B))[tid + 1024];
    float4 ev1 = ((const float4*)(wsf + OFF_E))[tid + 1024];
    {
        int p;
        p = (int)fmaf(bv0.x, HSCALE, 512.f); atomicAdd(&hb_par[par][min(max(p,0),NBINS-1)], 1u);
        p = (int)fmaf(bv0.y, HSCALE, 512.f); atomicAdd(&hb_par[par][min(max(p,0),NBINS-1)], 1u);
        p = (int)fmaf(bv0.z, HSCALE, 512.f); atomicAdd(&hb_par[par][min(max(p,0),NBINS-1)], 1u);
        p = (int)fmaf(bv0.w, HSCALE, 512.f); atomicAdd(&hb_par[par][min(max(p,0),NBINS-1)], 1u);
        p = (int)fmaf(bv1.x, HSCALE, 512.f); atomicAdd(&hb_par[par][min(max(p,0),NBINS-1)], 1u);
        p = (int)fmaf(bv1.y, HSCALE, 512.f); atomicAdd(&hb_par[par][min(max(p,0),NBINS-1)], 1u);
        p = (int)fmaf(bv1.z, HSCALE, 512.f); atomicAdd(&hb_par[par][min(max(p,0),NBINS-1)], 1u);
        p = (int)fmaf(bv1.w, HSCALE, 512.f); atomicAdd(&hb_par[par][min(max(p,0),NBINS-1)], 1u);
        p = (int)fmaf(ev0.x, HSCALE, 512.f); atomicAdd(&he_par[par][min(max(p,0),NBINS-1)], 1u);
        p = (int)fmaf(ev0.y, HSCALE, 512.f); atomicAdd(&he_par[par][min(max(p,0),NBINS-1)], 1u);
        p = (int)fmaf(ev0.z, HSCALE, 512.f); atomicAdd(&he_par[par][min(max(p,0),NBINS-1)], 1u);
        p = (int)fmaf(ev0.w, HSCALE, 512.f); atomicAdd(&he_par[par][min(max(p,0),NBINS-1)], 1u);
        p = (int)fmaf(ev1.x, HSCALE, 512.f); atomicAdd(&he_par[par][min(max(p,0),NBINS-1)], 1u);
        p = (int)fmaf(ev1.y, HSCALE, 512.f); atomicAdd(&he_par[par][min(max(p,0),NBINS-1)], 1u);
        p = (int)fmaf(ev1.z, HSCALE, 512.f); atomicAdd(&he_par[par][min(max(p,0),NBINS-1)], 1u);
        p = (int)fmaf(ev1.w, HSCALE, 512.f); atomicAdd(&he_par[par][min(max(p,0),NBINS-1)], 1u);
    }

    // ---- Reduce per-block exp partials (fixed order, validated absmax 0).
    float psb = wsf[OFF_PB + tid] + wsf[OFF_PB + 1024 + tid];
    float pse = wsf[OFF_PE + tid] + wsf[OFF_PE + 1024 + tid];
    for (int off = 32; off; off >>= 1) {
        psb += __shfl_xor(psb, off, 64);
        pse += __shfl_xor(pse, off, 64);
    }
    if (lane == 0) { fr_sb[wave] = psb; fr_se[wave] = pse; }
    __syncthreads();    // hist atomics + fr writes complete

    // ---- Merge parity hists (in place for b), top-bin bounds, suffix scan.
    unsigned hb = hb_par[0][tid] + hb_par[1][tid];
    unsigned he = he_par[0][tid] + he_par[1][tid];
    hb_par[0][tid] = hb;                      // merged b-hist for descent
    int ebin = (he != 0u) ? tid : -1;
    int bbin = (hb != 0u) ? tid : -1;
    for (int off = 32; off; off >>= 1) {
        ebin = max(ebin, __shfl_xor(ebin, off, 64));
        bbin = max(bbin, __shfl_xor(bbin, off, 64));
    }
    if (lane == 0) { fr_eb[wave] = ebin; fr_bb[wave] = bbin; }
    unsigned v = he;                          // intra-wave right-inclusive scan
    for (int off = 1; off < 64; off <<= 1) {
        unsigned t = __shfl_down(v, off, 64);
        if (lane + off < 64) v += t;
    }
    if (lane == 0) wtail_s[wave] = v;
    __syncthreads();
    if (tid == 0) {
        float a = 0.f, b = 0.f; int c = -1, d = -1;
        for (int i = 0; i < 16; ++i) {
            a += fr_sb[i]; b += fr_se[i];
            c = max(c, fr_eb[i]); d = max(d, fr_bb[i]);
        }
        sums_s[0] = a; sums_s[1] = b;
        sums_s[2] = -8.0f + (float)(c + 1) * BINW;   // >= true emax
        sums_s[3] = -8.0f + (float)(d + 1) * BINW;   // >= true bmax
        unsigned acc = 0, tails[16];
        for (int w = 15; w >= 0; --w) { tails[w] = acc; acc += wtail_s[w]; }
        for (int w = 0; w < 16; ++w) wtail_s[w] = tails[w];
    }
    __syncthreads();
    sfx[tid] = v + wtail_s[wave];
    __syncthreads();

    // ---- 32-ary descent, 2 rounds: largest t in [1,1024] with cnt(t)>=200.
    // cnt monotone non-increasing in t => identical t* to the 16-ary version.
    const unsigned TARGET = 2u * KK;
    int half = lane >> 5, l5 = lane & 31;
    int chunk = 32;
    for (int round = 0; round < 2; ++round) {
        int t = lo_s + (2 * wave + half + 1) * chunk;
        unsigned c = 0;
        for (int k = 0; k < 32; ++k) {
            int p = l5 + (k << 5);
            int idx = t + 512 - p;
            unsigned sv = (idx <= 0) ? sfx[0] : ((idx > NBINS - 1) ? 0u : sfx[idx]);
            c += hb_par[0][p] * sv;
        }
        for (int off = 16; off; off >>= 1) c += __shfl_xor(c, off, 64);
        if (l5 == 0) wred[2 * wave + half] = c;
        __syncthreads();
        if (tid == 0) {
            for (int w = 31; w >= 0; --w)
                if (wred[w] >= TARGET) { lo_s += (w + 1) * chunk; break; }
        }
        __syncthreads();
        chunk >>= 5;   // 32 -> 1
    }
    float thr = -8.0f + (float)(lo_s - 1) * BINW;   // one-bin safety margin
    float emax = sums_s[2], bmax = sums_s[3];

    // ---- Candidate rows/cols straight from registers (no LDS re-read).
#define CANDB(val, row)                                                    \
    if ((val) + emax >= thr) {                                             \
        unsigned pos = atomicAdd(&nrows_s, 1u);                            \
        if (pos < ROW_CAP) { rows_s[pos] = (row); rowb_s[pos] = (val); }   \
    }
#define CANDE(val, row)                                                    \
    if ((val) + bmax >= thr) {                                             \
        unsigned pos = atomicAdd(&ncols_s, 1u);                            \
        if (pos < COL_CAP) { cols_s[pos] = (row); cole_s[pos] = (val); }   \
    }
    {
        int r0 = 4 * tid, r1 = 4 * (tid + 1024);
        CANDB(bv0.x, r0 + 0) CANDB(bv0.y, r0 + 1) CANDB(bv0.z, r0 + 2) CANDB(bv0.w, r0 + 3)
        CANDB(bv1.x, r1 + 0) CANDB(bv1.y, r1 + 1) CANDB(bv1.z, r1 + 2) CANDB(bv1.w, r1 + 3)
        CANDE(ev0.x, r0 + 0) CANDE(ev0.y, r0 + 1) CANDE(ev0.z, r0 + 2) CANDE(ev0.w, r0 + 3)
        CANDE(ev1.x, r1 + 0) CANDE(ev1.y, r1 + 1) CANDE(ev1.z, r1 + 2) CANDE(ev1.w, r1 + 3)
    }
    __syncthreads();
    int nr = (int)min(nrows_s, (unsigned)ROW_CAP);
    int nc = (int)min(ncols_s, (unsigned)COL_CAP);

    // ---- Pair scan over nr x nc, upper triangle (j >= r); append packed key.
    int tot = nr * nc;
    for (int idx = tid; idx < tot; idx += 1024) {
        int ri = idx / nc, cj = idx - ri * nc;
        int r = rows_s[ri], j = cols_s[cj];
        if (j < r) continue;
        float s = rowb_s[ri] + cole_s[cj];
        if (s >= thr) {
            unsigned pos = atomicAdd(&ncand_s, 1u);
            if (pos < CAND_CAP) {
                unsigned fi = ((unsigned)r << 13) | (unsigned)j;
                kv[pos] = ((unsigned long long)ford(s) << 32) | (unsigned)(~fi);
            }
        }
    }
    __syncthreads();

    // ---- Rank-based top-100 on packed keys (value desc, flat index asc).
    unsigned M = min(ncand_s, (unsigned)CAND_CAP);
    float inv_den = 1.0f / (sums_s[0] * sums_s[1]);
    for (unsigned c2 = tid; c2 < M; c2 += 1024) {
        unsigned long long kk = kv[c2];
        int rank = 0;
        for (unsigned m = 0; m < M; ++m) rank += (kv[m] > kk);
        if (rank < KK) {
            unsigned hi = (unsigned)(kk >> 32);
            unsigned fi = ~(unsigned)kk;
            unsigned u = (hi & 0x80000000u) ? (hi ^ 0x80000000u) : ~hi;
            float vv = __uint_as_float(u);
            out[2 * rank]     = (float)(fi >> 13);
            out[2 * rank + 1] = (float)(fi & 8191u);
            out[200 + rank]   = expf(vv) * inv_den;
        }
    }
}

extern "C" void kernel_launch(void* const* d_in, const int* in_sizes, int n_in,
                              void* d_out, int out_size, void* d_ws, size_t ws_size,
                              hipStream_t stream) {
    const float* G  = (const float*)d_in[0];
    const float* wb = (const float*)d_in[1];
    const float* we = (const float*)d_in[2];
    float* out = (float*)d_out;
    float* wsf = (float*)d_ws;

    hipLaunchKernelGGL(k_be, dim3(2048), dim3(256), 0, stream, G, wb, we, wsf);
    hipLaunchKernelGGL(k_tail, dim3(1), dim3(1024), 0, stream, wsf, out);
}

// Round 6
// 75.333 us; speedup vs baseline: 2.9696x; 1.0311x over previous
//
#include <hip/hip_runtime.h>
#include <math.h>

// Problem constants (reference: N=8192, D=200, k=100)
#define NN 8192
#define DD 200
#define KK 100

// s = b_i + e_j histogram grid: 1024 bins over [-8, 8), width 2^-6 (exact fp)
#define NBINS 1024
#define HSCALE 64.0f
#define BINW 0.015625f
#define CAND_CAP 4096
#define ROW_CAP 1024
#define COL_CAP 1024

// ws layout (4-byte word offsets)
#define OFF_B 0
#define OFF_E 8192
#define OFF_PB 16384   // 2048 per-block partials of sum(exp(b))
#define OFF_PE 18432   // 2048 per-block partials of sum(exp(e))

// K1: b[i] = G[i,:]·wb, e[i] = G[i,:]·we. One wave per row; 50 lanes × float4.
// Measured R4: ~1.24 us (~5.3 TB/s on G) — at the HBM floor; unchanged.
__global__ __launch_bounds__(256) void k_be(const float* __restrict__ G,
                                            const float* __restrict__ wb,
                                            const float* __restrict__ we,
                                            float* __restrict__ wsf) {
    __shared__ float seb[4], see[4];
    int gid = blockIdx.x * 256 + threadIdx.x;
    int row = gid >> 6;
    int lane = gid & 63;
    int wave = threadIdx.x >> 6;
    float pb = 0.f, pe = 0.f;
    if (lane < 50) {
        float4 g = ((const float4*)(G + (size_t)row * DD))[lane];
        float4 B = ((const float4*)wb)[lane];
        float4 E = ((const float4*)we)[lane];
        pb = fmaf(g.x, B.x, fmaf(g.y, B.y, fmaf(g.z, B.z, g.w * B.w)));
        pe = fmaf(g.x, E.x, fmaf(g.y, E.y, fmaf(g.z, E.z, g.w * E.w)));
    }
    for (int off = 32; off; off >>= 1) {
        pb += __shfl_xor(pb, off, 64);
        pe += __shfl_xor(pe, off, 64);
    }
    if (lane == 0) {
        wsf[OFF_B + row] = pb;
        wsf[OFF_E + row] = pe;
        seb[wave] = expf(pb);
        see[wave] = expf(pe);
    }
    __syncthreads();
    if (threadIdx.x == 0) {
        wsf[OFF_PB + blockIdx.x] = (seb[0] + seb[1]) + (seb[2] + seb[3]);
        wsf[OFF_PE + blockIdx.x] = (see[0] + see[1]) + (see[2] + see[3]);
    }
}

// Order-preserving float->uint (total order, matches > on non-NaN floats).
__device__ __forceinline__ unsigned ford(float f) {
    unsigned u = __float_as_uint(f);
    return u ^ ((u & 0x80000000u) ? 0xFFFFFFFFu : 0x80000000u);
}

// K2: single block, 1024 threads. R6: zero serial tid0 sections (all merges
// are all-lane redundant shfl trees / ballot+clz), 8 barriers (was 11),
// 4-way privatized hists, lo/thr/sums live in registers. Identical integer
// threshold math => identical t*, candidate sets, indices.
__global__ __launch_bounds__(1024) void k_tail(const float* __restrict__ wsf,
                                               float* __restrict__ out) {
    __shared__ unsigned long long kv[CAND_CAP];   // 32 KB packed (value,~idx)
    __shared__ unsigned hb_par[4][NBINS];         // 16 KB ([0] becomes merged)
    __shared__ unsigned he_par[4][NBINS];         // 16 KB
    __shared__ unsigned sfx[NBINS];               // 4 KB suffix sums of hist_e
    __shared__ int      rows_s[ROW_CAP];
    __shared__ float    rowb_s[ROW_CAP];
    __shared__ int      cols_s[COL_CAP];
    __shared__ float    cole_s[COL_CAP];
    __shared__ float    fr_sb[16], fr_se[16];
    __shared__ int      fr_eb[16], fr_bb[16];
    __shared__ unsigned wtail_s[16];
    __shared__ unsigned wred[32], wred2[32];
    __shared__ unsigned nrows_s, ncols_s, ncand_s;

    int tid = threadIdx.x, wave = tid >> 6, lane = tid & 63;
    int par = wave & 3;

    hb_par[0][tid] = 0u; hb_par[1][tid] = 0u; hb_par[2][tid] = 0u; hb_par[3][tid] = 0u;
    he_par[0][tid] = 0u; he_par[1][tid] = 0u; he_par[2][tid] = 0u; he_par[3][tid] = 0u;
    if (tid == 0) { nrows_s = 0u; ncols_s = 0u; ncand_s = 0u; }
    __syncthreads();                                              // B1

    // ---- Registers hold b,e (rows 4*tid.. and +4096); 4-way LDS hists.
    float4 bv0 = ((const float4*)(wsf + OFF_B))[tid];
    float4 ev0 = ((const float4*)(wsf + OFF_E))[tid];
    float4 bv1 = ((const float4*)(wsf + OFF_B))[tid + 1024];
    float4 ev1 = ((const float4*)(wsf + OFF_E))[tid + 1024];
    float p0 = wsf[OFF_PB + tid], p1 = wsf[OFF_PB + 1024 + tid];
    float q0 = wsf[OFF_PE + tid], q1 = wsf[OFF_PE + 1024 + tid];
    {
        int p;
        p = (int)fmaf(bv0.x, HSCALE, 512.f); atomicAdd(&hb_par[par][min(max(p,0),NBINS-1)], 1u);
        p = (int)fmaf(bv0.y, HSCALE, 512.f); atomicAdd(&hb_par[par][min(max(p,0),NBINS-1)], 1u);
        p = (int)fmaf(bv0.z, HSCALE, 512.f); atomicAdd(&hb_par[par][min(max(p,0),NBINS-1)], 1u);
        p = (int)fmaf(bv0.w, HSCALE, 512.f); atomicAdd(&hb_par[par][min(max(p,0),NBINS-1)], 1u);
        p = (int)fmaf(bv1.x, HSCALE, 512.f); atomicAdd(&hb_par[par][min(max(p,0),NBINS-1)], 1u);
        p = (int)fmaf(bv1.y, HSCALE, 512.f); atomicAdd(&hb_par[par][min(max(p,0),NBINS-1)], 1u);
        p = (int)fmaf(bv1.z, HSCALE, 512.f); atomicAdd(&hb_par[par][min(max(p,0),NBINS-1)], 1u);
        p = (int)fmaf(bv1.w, HSCALE, 512.f); atomicAdd(&hb_par[par][min(max(p,0),NBINS-1)], 1u);
        p = (int)fmaf(ev0.x, HSCALE, 512.f); atomicAdd(&he_par[par][min(max(p,0),NBINS-1)], 1u);
        p = (int)fmaf(ev0.y, HSCALE, 512.f); atomicAdd(&he_par[par][min(max(p,0),NBINS-1)], 1u);
        p = (int)fmaf(ev0.z, HSCALE, 512.f); atomicAdd(&he_par[par][min(max(p,0),NBINS-1)], 1u);
        p = (int)fmaf(ev0.w, HSCALE, 512.f); atomicAdd(&he_par[par][min(max(p,0),NBINS-1)], 1u);
        p = (int)fmaf(ev1.x, HSCALE, 512.f); atomicAdd(&he_par[par][min(max(p,0),NBINS-1)], 1u);
        p = (int)fmaf(ev1.y, HSCALE, 512.f); atomicAdd(&he_par[par][min(max(p,0),NBINS-1)], 1u);
        p = (int)fmaf(ev1.z, HSCALE, 512.f); atomicAdd(&he_par[par][min(max(p,0),NBINS-1)], 1u);
        p = (int)fmaf(ev1.w, HSCALE, 512.f); atomicAdd(&he_par[par][min(max(p,0),NBINS-1)], 1u);
    }
    // exp-partial wave reduce (same order as R5)
    float psb = p0 + p1, pse = q0 + q1;
    for (int off = 32; off; off >>= 1) {
        psb += __shfl_xor(psb, off, 64);
        pse += __shfl_xor(pse, off, 64);
    }
    if (lane == 0) { fr_sb[wave] = psb; fr_se[wave] = pse; }
    __syncthreads();                                              // B2

    // ---- Merge parity hists; per-wave bounds + intra-wave suffix scan.
    unsigned hb = hb_par[0][tid] + hb_par[1][tid] + hb_par[2][tid] + hb_par[3][tid];
    unsigned he = he_par[0][tid] + he_par[1][tid] + he_par[2][tid] + he_par[3][tid];
    hb_par[0][tid] = hb;                      // merged b-hist for descent
    int ebin = (he != 0u) ? tid : -1;
    int bbin = (hb != 0u) ? tid : -1;
    for (int off = 32; off; off >>= 1) {
        ebin = max(ebin, __shfl_xor(ebin, off, 64));
        bbin = max(bbin, __shfl_xor(bbin, off, 64));
    }
    if (lane == 0) { fr_eb[wave] = ebin; fr_bb[wave] = bbin; }
    unsigned v = he;                          // intra-wave right-inclusive scan
    for (int off = 1; off < 64; off <<= 1) {
        unsigned t = __shfl_down(v, off, 64);
        if (lane + off < 64) v += t;
    }
    if (lane == 0) wtail_s[wave] = v;
    __syncthreads();                                              // B3

    // ---- All-lane redundant merges (no tid0 serial sections).
    int w16 = lane & 15;
    float sb = fr_sb[w16], se = fr_se[w16];
    int eb = fr_eb[w16], bb = fr_bb[w16];
    unsigned wt = wtail_s[w16];
    if (w16 <= wave) wt = 0u;                 // keep only waves after mine
    for (int off = 8; off; off >>= 1) {
        sb += __shfl_xor(sb, off, 64);
        se += __shfl_xor(se, off, 64);
        eb = max(eb, __shfl_xor(eb, off, 64));
        bb = max(bb, __shfl_xor(bb, off, 64));
        wt += __shfl_xor(wt, off, 64);
    }
    sfx[tid] = v + wt;                        // global suffix sum of hist_e
    float emax = -8.0f + (float)(eb + 1) * BINW;   // >= true emax
    float bmax = -8.0f + (float)(bb + 1) * BINW;   // >= true bmax
    float inv_den = 1.0f / (sb * se);
    __syncthreads();                                              // B4

    // ---- 32-ary descent, 2 rounds, ballot-selected (identical t*).
    const unsigned TARGET = 2u * KK;
    int half = lane >> 5, l5 = lane & 31;
    int lo = 0;
    {   // round 1, chunk = 32
        int t = (2 * wave + half + 1) * 32;
        unsigned c = 0;
        for (int k = 0; k < 32; ++k) {
            int p = l5 + (k << 5);
            int idx = t + 512 - p;
            unsigned sv = (idx <= 0) ? sfx[0] : ((idx > NBINS - 1) ? 0u : sfx[idx]);
            c += hb_par[0][p] * sv;
        }
        for (int off = 16; off; off >>= 1) c += __shfl_xor(c, off, 64);
        if (l5 == 0) wred[2 * wave + half] = c;
    }
    __syncthreads();                                              // B5
    {
        unsigned cc = wred[lane & 31];
        unsigned long long mk = __ballot(cc >= TARGET);
        unsigned m32 = (unsigned)(mk & 0xFFFFFFFFull);
        if (m32) lo += (32 - __builtin_clz(m32)) * 32;   // (w_sel+1)*chunk
    }
    {   // round 2, chunk = 1 (writes wred2: WAR-safe without a barrier)
        int t = lo + (2 * wave + half + 1);
        unsigned c = 0;
        for (int k = 0; k < 32; ++k) {
            int p = l5 + (k << 5);
            int idx = t + 512 - p;
            unsigned sv = (idx <= 0) ? sfx[0] : ((idx > NBINS - 1) ? 0u : sfx[idx]);
            c += hb_par[0][p] * sv;
        }
        for (int off = 16; off; off >>= 1) c += __shfl_xor(c, off, 64);
        if (l5 == 0) wred2[2 * wave + half] = c;
    }
    __syncthreads();                                              // B6
    {
        unsigned cc = wred2[lane & 31];
        unsigned long long mk = __ballot(cc >= TARGET);
        unsigned m32 = (unsigned)(mk & 0xFFFFFFFFull);
        if (m32) lo += (32 - __builtin_clz(m32));
    }
    float thr = -8.0f + (float)(lo - 1) * BINW;   // one-bin safety margin

    // ---- Candidate rows/cols straight from registers.
#define CANDB(val, row)                                                    \
    if ((val) + emax >= thr) {                                             \
        unsigned pos = atomicAdd(&nrows_s, 1u);                            \
        if (pos < ROW_CAP) { rows_s[pos] = (row); rowb_s[pos] = (val); }   \
    }
#define CANDE(val, row)                                                    \
    if ((val) + bmax >= thr) {                                             \
        unsigned pos = atomicAdd(&ncols_s, 1u);                            \
        if (pos < COL_CAP) { cols_s[pos] = (row); cole_s[pos] = (val); }   \
    }
    {
        int r0 = 4 * tid, r1 = 4 * (tid + 1024);
        CANDB(bv0.x, r0 + 0) CANDB(bv0.y, r0 + 1) CANDB(bv0.z, r0 + 2) CANDB(bv0.w, r0 + 3)
        CANDB(bv1.x, r1 + 0) CANDB(bv1.y, r1 + 1) CANDB(bv1.z, r1 + 2) CANDB(bv1.w, r1 + 3)
        CANDE(ev0.x, r0 + 0) CANDE(ev0.y, r0 + 1) CANDE(ev0.z, r0 + 2) CANDE(ev0.w, r0 + 3)
        CANDE(ev1.x, r1 + 0) CANDE(ev1.y, r1 + 1) CANDE(ev1.z, r1 + 2) CANDE(ev1.w, r1 + 3)
    }
    __syncthreads();                                              // B7
    int nr = (int)min(nrows_s, (unsigned)ROW_CAP);
    int nc = (int)min(ncols_s, (unsigned)COL_CAP);

    // ---- Pair scan over nr x nc, upper triangle (j >= r); append packed key.
    int tot = nr * nc;
    for (int idx = tid; idx < tot; idx += 1024) {
        int ri = idx / nc, cj = idx - ri * nc;
        int r = rows_s[ri], j = cols_s[cj];
        if (j < r) continue;
        float s = rowb_s[ri] + cole_s[cj];
        if (s >= thr) {
            unsigned pos = atomicAdd(&ncand_s, 1u);
            if (pos < CAND_CAP) {
                unsigned fi = ((unsigned)r << 13) | (unsigned)j;
                kv[pos] = ((unsigned long long)ford(s) << 32) | (unsigned)(~fi);
            }
        }
    }
    __syncthreads();                                              // B8

    // ---- Rank-based top-100 on packed keys (value desc, flat index asc).
    unsigned M = min(ncand_s, (unsigned)CAND_CAP);
    for (unsigned c2 = tid; c2 < M; c2 += 1024) {
        unsigned long long kk = kv[c2];
        int rank = 0;
        for (unsigned m = 0; m < M; ++m) rank += (kv[m] > kk);
        if (rank < KK) {
            unsigned hi = (unsigned)(kk >> 32);
            unsigned fi = ~(unsigned)kk;
            unsigned u = (hi & 0x80000000u) ? (hi ^ 0x80000000u) : ~hi;
            float vv = __uint_as_float(u);
            out[2 * rank]     = (float)(fi >> 13);
            out[2 * rank + 1] = (float)(fi & 8191u);
            out[200 + rank]   = expf(vv) * inv_den;
        }
    }
}

extern "C" void kernel_launch(void* const* d_in, const int* in_sizes, int n_in,
                              void* d_out, int out_size, void* d_ws, size_t ws_size,
                              hipStream_t stream) {
    const float* G  = (const float*)d_in[0];
    const float* wb = (const float*)d_in[1];
    const float* we = (const float*)d_in[2];
    float* out = (float*)d_out;
    float* wsf = (float*)d_ws;

    hipLaunchKernelGGL(k_be, dim3(2048), dim3(256), 0, stream, G, wb, we, wsf);
    hipLaunchKernelGGL(k_tail, dim3(1), dim3(1024), 0, stream, wsf, out);
}